// Round 1
// baseline (522.456 us; speedup 1.0000x reference)
//
#include <hip/hip_runtime.h>
#include <hip/hip_bf16.h>
#include <math.h>

typedef __bf16 bf16;
typedef __bf16 bf16x4 __attribute__((ext_vector_type(4)));
typedef __bf16 bf16x8 __attribute__((ext_vector_type(8)));
typedef float f32x4 __attribute__((ext_vector_type(4)));
typedef unsigned int uint32x4 __attribute__((ext_vector_type(4)));

// ---------------------------------------------------------------- helpers
__device__ __forceinline__ void gload_lds16(const void* g, void* l) {
  __builtin_amdgcn_global_load_lds(
      (const __attribute__((address_space(1))) void*)g,
      (__attribute__((address_space(3))) void*)l, 16, 0, 0);
}

// ---------------------------------------------------------------- f32 -> bf16
__global__ void cvt_f32_bf16(const float* __restrict__ in, bf16* __restrict__ out, int n) {
  int stride = gridDim.x * blockDim.x;
  for (int i = blockIdx.x * blockDim.x + threadIdx.x; i * 4 < n; i += stride) {
    float4 v = *(const float4*)(in + (size_t)i * 4);
    bf16x4 o;
    o[0] = (bf16)v.x; o[1] = (bf16)v.y; o[2] = (bf16)v.z; o[3] = (bf16)v.w;
    *(bf16x4*)(out + (size_t)i * 4) = o;
  }
}

// ---------------------------------------------------------------- NT GEMM
// C[M,N] = alpha * A[M,K] @ B[N,K]^T    (m97 structure: 128x128 tile, BK=32)
template <typename OutT>
__global__ __launch_bounds__(256)
void gemm_nt(const bf16* __restrict__ A, const bf16* __restrict__ B,
             OutT* __restrict__ C, int M, int N, int K, float alpha) {
  __shared__ __align__(16) char smem[16384];  // A-tile 8KB [128][32], B-tile 8KB

  const int lane = threadIdx.x & 63;
  const int w    = threadIdx.x >> 6;   // 4 waves
  const int wr   = w >> 1, wc = w & 1; // 2x2 wave grid, 64x64 per wave
  const int brow = blockIdx.y, bcol = blockIdx.x;

  f32x4 acc[4][4] = {};

  const bf16* Ab = A + (size_t)brow * 128 * K;
  const bf16* Bb = B + (size_t)bcol * 128 * K;

  const int srow = w * 32 + (lane >> 2);   // staging row within tile (per instr half)
  const int skc  = (lane & 3) * 8;         // staging k-chunk (8 bf16 = 16B)

  for (int k0 = 0; k0 < K; k0 += 32) {
    gload_lds16(Ab + (size_t)srow * K + k0 + skc,        smem + w * 2048);
    gload_lds16(Ab + (size_t)(srow + 16) * K + k0 + skc, smem + w * 2048 + 1024);
    gload_lds16(Bb + (size_t)srow * K + k0 + skc,        smem + 8192 + w * 2048);
    gload_lds16(Bb + (size_t)(srow + 16) * K + k0 + skc, smem + 8192 + w * 2048 + 1024);
    __syncthreads();

    bf16x8 af[4], bfr[4];
#pragma unroll
    for (int i = 0; i < 4; ++i) {
      af[i]  = *(const bf16x8*)(smem + ((wr * 64 + i * 16 + (lane & 15)) * 64 + (lane >> 4) * 16));
      bfr[i] = *(const bf16x8*)(smem + 8192 + ((wc * 64 + i * 16 + (lane & 15)) * 64 + (lane >> 4) * 16));
    }
#pragma unroll
    for (int mi = 0; mi < 4; ++mi)
#pragma unroll
      for (int ni = 0; ni < 4; ++ni)
        acc[mi][ni] = __builtin_amdgcn_mfma_f32_16x16x32_bf16(af[mi], bfr[ni], acc[mi][ni], 0, 0, 0);
    __syncthreads();
  }

  // epilogue: D layout row=(lane>>4)*4+j, col=lane&15
  const int r0 = brow * 128 + wr * 64 + (lane >> 4) * 4;
  const int c0 = bcol * 128 + wc * 64 + (lane & 15);
#pragma unroll
  for (int mi = 0; mi < 4; ++mi)
#pragma unroll
    for (int ni = 0; ni < 4; ++ni)
#pragma unroll
      for (int j = 0; j < 4; ++j)
        C[(size_t)(r0 + mi * 16 + j) * N + c0 + ni * 16] = (OutT)(acc[mi][ni][j] * alpha);
}

// ---------------------------------------------------------------- flash attention (causal GQA)
// Q: [B*T, 2048] (head h at col h*128, pre-scaled), K/V: [B*T, 512] (kv head at col kv*128)
// AO: [B*T, 2048]. Block: 128 q-rows, 4 waves x 32 rows. KV tile = 32.
__global__ __launch_bounds__(256)
void attn_fwd(const bf16* __restrict__ Q, const bf16* __restrict__ Kt,
              const bf16* __restrict__ Vt, bf16* __restrict__ AO) {
  const int T = 2048, C = 2048, KVD = 512, HD = 128;
  const int qt = blockIdx.x, h = blockIdx.y, b = blockIdx.z;
  const int kvh = h >> 2;
  const int lane = threadIdx.x & 63, w = threadIdx.x >> 6;

  __shared__ __align__(16) char sK[8192];        // [32][128] bf16, XOR-swizzled rows
  __shared__ __align__(16) bf16 sV[128][40];     // V^T (hd x kv), padded rows
  __shared__ __align__(16) bf16 sP[4][32][40];   // per-wave P, padded rows

  const bf16* Qg = Q  + (size_t)b * T * C   + (size_t)h   * HD;
  const bf16* Kg = Kt + (size_t)b * T * KVD + (size_t)kvh * HD;
  const bf16* Vg = Vt + (size_t)b * T * KVD + (size_t)kvh * HD;

  const int q0 = qt * 128;
  const int qw = q0 + w * 32;  // this wave's first q row

  // Q fragments in registers: A-layout, lane holds Q[qw+m*16+(lane&15)][kk*32+(lane>>4)*8 ..+8]
  bf16x8 qf[2][4];
#pragma unroll
  for (int m = 0; m < 2; ++m)
#pragma unroll
    for (int kk = 0; kk < 4; ++kk)
      qf[m][kk] = *(const bf16x8*)(Qg + (size_t)(qw + m * 16 + (lane & 15)) * C + kk * 32 + (lane >> 4) * 8);

  f32x4 o[2][8] = {};
  float mstat[2][4], lstat[2][4];
#pragma unroll
  for (int m = 0; m < 2; ++m)
#pragma unroll
    for (int j = 0; j < 4; ++j) { mstat[m][j] = -INFINITY; lstat[m][j] = 0.f; }

  const int ntiles = (q0 + 128) / 32;
  for (int t = 0; t < ntiles; ++t) {
    const int kv0 = t * 32;
    // ---- stage K (swizzled) and V^T (transposed, padded)
    for (int s = threadIdx.x; s < 512; s += 256) {
      const int r = s >> 4, ch = s & 15;
      uint32x4 kval = *(const uint32x4*)(Kg + (size_t)(kv0 + r) * KVD + ch * 8);
      int ba = r * 256 + ch * 16;
      ba ^= (r & 7) << 4;
      *(uint32x4*)(sK + ba) = kval;
      bf16x8 vv = *(const bf16x8*)(Vg + (size_t)(kv0 + r) * KVD + ch * 8);
#pragma unroll
      for (int i = 0; i < 8; ++i) sV[ch * 8 + i][r] = vv[i];
    }
    __syncthreads();

    if (kv0 <= qw + 31) {
      // ---- QK^T : S[32 q][32 kv]
      f32x4 s_[2][2] = {};
#pragma unroll
      for (int kk = 0; kk < 4; ++kk) {
        bf16x8 kf[2];
#pragma unroll
        for (int n = 0; n < 2; ++n) {
          const int r = n * 16 + (lane & 15);
          int ba = r * 256 + kk * 64 + (lane >> 4) * 16;
          ba ^= (r & 7) << 4;
          kf[n] = *(const bf16x8*)(sK + ba);
        }
#pragma unroll
        for (int m = 0; m < 2; ++m)
#pragma unroll
          for (int n = 0; n < 2; ++n)
            s_[m][n] = __builtin_amdgcn_mfma_f32_16x16x32_bf16(qf[m][kk], kf[n], s_[m][n], 0, 0, 0);
      }
      // ---- causal mask (only near diagonal)
      if (kv0 + 31 > qw) {
#pragma unroll
        for (int m = 0; m < 2; ++m)
#pragma unroll
          for (int n = 0; n < 2; ++n)
#pragma unroll
            for (int j = 0; j < 4; ++j) {
              const int qr = qw + m * 16 + (lane >> 4) * 4 + j;
              const int kc = kv0 + n * 16 + (lane & 15);
              if (kc > qr) s_[m][n][j] = -1e30f;
            }
      }
      // ---- online softmax (row = (lane>>4)*4+j within m-subtile)
#pragma unroll
      for (int m = 0; m < 2; ++m)
#pragma unroll
        for (int j = 0; j < 4; ++j) {
          float pm = fmaxf(s_[m][0][j], s_[m][1][j]);
          pm = fmaxf(pm, __shfl_xor(pm, 1));
          pm = fmaxf(pm, __shfl_xor(pm, 2));
          pm = fmaxf(pm, __shfl_xor(pm, 4));
          pm = fmaxf(pm, __shfl_xor(pm, 8));
          const float mn = fmaxf(mstat[m][j], pm);
          const float rs = __expf(mstat[m][j] - mn);
          mstat[m][j] = mn;
          const float p0 = __expf(s_[m][0][j] - mn);
          const float p1 = __expf(s_[m][1][j] - mn);
          s_[m][0][j] = p0; s_[m][1][j] = p1;
          float ls = p0 + p1;
          ls += __shfl_xor(ls, 1);
          ls += __shfl_xor(ls, 2);
          ls += __shfl_xor(ls, 4);
          ls += __shfl_xor(ls, 8);
          lstat[m][j] = lstat[m][j] * rs + ls;
#pragma unroll
          for (int n = 0; n < 8; ++n) o[m][n][j] *= rs;
        }
      // ---- P -> LDS (D layout write), reread in A layout
#pragma unroll
      for (int m = 0; m < 2; ++m)
#pragma unroll
        for (int n = 0; n < 2; ++n)
#pragma unroll
          for (int j = 0; j < 4; ++j)
            sP[w][m * 16 + (lane >> 4) * 4 + j][n * 16 + (lane & 15)] = (bf16)s_[m][n][j];

      bf16x8 pa[2];
#pragma unroll
      for (int m = 0; m < 2; ++m)
        pa[m] = *(const bf16x8*)&sP[w][m * 16 + (lane & 15)][(lane >> 4) * 8];
#pragma unroll
      for (int n = 0; n < 8; ++n) {
        bf16x8 vb = *(const bf16x8*)&sV[n * 16 + (lane & 15)][(lane >> 4) * 8];
#pragma unroll
        for (int m = 0; m < 2; ++m)
          o[m][n] = __builtin_amdgcn_mfma_f32_16x16x32_bf16(pa[m], vb, o[m][n], 0, 0, 0);
      }
    }
    __syncthreads();
  }

  // ---- epilogue: O /= l, write bf16
  bf16* Og = AO + (size_t)b * T * C + (size_t)h * HD;
#pragma unroll
  for (int m = 0; m < 2; ++m)
#pragma unroll
    for (int j = 0; j < 4; ++j) {
      const float inv = 1.f / lstat[m][j];
      const int qr = qw + m * 16 + (lane >> 4) * 4 + j;
#pragma unroll
      for (int n = 0; n < 8; ++n)
        Og[(size_t)qr * C + n * 16 + (lane & 15)] = (bf16)(o[m][n][j] * inv);
    }
}

// ---------------------------------------------------------------- launch
extern "C" void kernel_launch(void* const* d_in, const int* in_sizes, int n_in,
                              void* d_out, int out_size, void* d_ws, size_t ws_size,
                              hipStream_t stream) {
  const int B = 2, T = 2048, C = 2048, KVD = 512;
  const int M = B * T;  // 4096

  const float* x  = (const float*)d_in[0];
  const float* Wq = (const float*)d_in[1];
  const float* Wk = (const float*)d_in[2];
  const float* Wv = (const float*)d_in[3];
  const float* Wo = (const float*)d_in[4];
  float* out = (float*)d_out;

  char* ws = (char*)d_ws;
  bf16* xb  = (bf16*)(ws);                    // 16,777,216 B
  bf16* wqb = (bf16*)(ws + 16777216);         //  8,388,608
  bf16* wkb = (bf16*)(ws + 25165824);         //  2,097,152
  bf16* wvb = (bf16*)(ws + 27262976);         //  2,097,152
  bf16* wob = (bf16*)(ws + 29360128);         //  8,388,608
  bf16* Qb  = (bf16*)(ws + 37748736);         // 16,777,216
  bf16* Kb  = (bf16*)(ws + 54525952);         //  4,194,304
  bf16* Vb  = (bf16*)(ws + 58720256);         //  4,194,304
  bf16* AOb = (bf16*)(ws + 62914560);         // 16,777,216  (end 79,691,776)

  auto conv = [&](const float* src, bf16* dst, int n) {
    int blocks = (n / 4 + 255) / 256;
    if (blocks > 2048) blocks = 2048;
    cvt_f32_bf16<<<blocks, 256, 0, stream>>>(src, dst, n);
  };
  conv(x,  xb,  M * C);
  conv(Wq, wqb, C * C);
  conv(Wk, wkb, KVD * C);
  conv(Wv, wvb, KVD * C);
  conv(Wo, wob, C * C);

  const float scale = 0.08838834764831845f;  // 128^-0.5, folded into Q
  gemm_nt<bf16><<<dim3(C / 128, M / 128), 256, 0, stream>>>(xb, wqb, Qb, M, C, C, scale);
  gemm_nt<bf16><<<dim3(KVD / 128, M / 128), 256, 0, stream>>>(xb, wkb, Kb, M, KVD, C, 1.0f);
  gemm_nt<bf16><<<dim3(KVD / 128, M / 128), 256, 0, stream>>>(xb, wvb, Vb, M, KVD, C, 1.0f);

  attn_fwd<<<dim3(T / 128, 16, B), 256, 0, stream>>>(Qb, Kb, Vb, AOb);

  gemm_nt<float><<<dim3(C / 128, M / 128), 256, 0, stream>>>(AOb, wob, out, M, C, C, 1.0f);
}

// Round 2
// 362.799 us; speedup vs baseline: 1.4401x; 1.4401x over previous
//
#include <hip/hip_runtime.h>
#include <hip/hip_bf16.h>
#include <math.h>

typedef __bf16 bf16;
typedef __bf16 bf16x4 __attribute__((ext_vector_type(4)));
typedef __bf16 bf16x8 __attribute__((ext_vector_type(8)));
typedef float f32x4 __attribute__((ext_vector_type(4)));

// ---------------------------------------------------------------- helpers
__device__ __forceinline__ void gload_lds16(const void* g, void* l) {
  __builtin_amdgcn_global_load_lds(
      (const __attribute__((address_space(1))) void*)g,
      (__attribute__((address_space(3))) void*)l, 16, 0, 0);
}

// ---------------------------------------------------------------- f32 -> bf16
__global__ void cvt_f32_bf16(const float* __restrict__ in, bf16* __restrict__ out, int n) {
  int stride = gridDim.x * blockDim.x;
  for (int i = blockIdx.x * blockDim.x + threadIdx.x; i * 4 < n; i += stride) {
    float4 v = *(const float4*)(in + (size_t)i * 4);
    bf16x4 o;
    o[0] = (bf16)v.x; o[1] = (bf16)v.y; o[2] = (bf16)v.z; o[3] = (bf16)v.w;
    *(bf16x4*)(out + (size_t)i * 4) = o;
  }
}

// ---------------------------------------------------------------- NT GEMM
// C[M,N] = alpha * A[M,K] @ B[N,K]^T ; TC=true stores C^T ([N][M])
template <typename OutT, bool TC>
__global__ __launch_bounds__(256)
void gemm_nt(const bf16* __restrict__ A, const bf16* __restrict__ B,
             OutT* __restrict__ C, int M, int N, int K, float alpha) {
  __shared__ __align__(16) char smem[16384];  // A-tile 8KB [128][32], B-tile 8KB

  const int lane = threadIdx.x & 63;
  const int w    = threadIdx.x >> 6;   // 4 waves
  const int wr   = w >> 1, wc = w & 1; // 2x2 wave grid, 64x64 per wave
  const int brow = blockIdx.y, bcol = blockIdx.x;

  f32x4 acc[4][4] = {};

  const bf16* Ab = A + (size_t)brow * 128 * K;
  const bf16* Bb = B + (size_t)bcol * 128 * K;

  const int srow = w * 32 + (lane >> 2);   // staging row within tile
  const int skc  = (lane & 3) * 8;         // staging k-chunk (8 bf16 = 16B)

  for (int k0 = 0; k0 < K; k0 += 32) {
    gload_lds16(Ab + (size_t)srow * K + k0 + skc,        smem + w * 2048);
    gload_lds16(Ab + (size_t)(srow + 16) * K + k0 + skc, smem + w * 2048 + 1024);
    gload_lds16(Bb + (size_t)srow * K + k0 + skc,        smem + 8192 + w * 2048);
    gload_lds16(Bb + (size_t)(srow + 16) * K + k0 + skc, smem + 8192 + w * 2048 + 1024);
    __syncthreads();

    bf16x8 af[4], bfr[4];
#pragma unroll
    for (int i = 0; i < 4; ++i) {
      af[i]  = *(const bf16x8*)(smem + ((wr * 64 + i * 16 + (lane & 15)) * 64 + (lane >> 4) * 16));
      bfr[i] = *(const bf16x8*)(smem + 8192 + ((wc * 64 + i * 16 + (lane & 15)) * 64 + (lane >> 4) * 16));
    }
#pragma unroll
    for (int mi = 0; mi < 4; ++mi)
#pragma unroll
      for (int ni = 0; ni < 4; ++ni)
        acc[mi][ni] = __builtin_amdgcn_mfma_f32_16x16x32_bf16(af[mi], bfr[ni], acc[mi][ni], 0, 0, 0);
    __syncthreads();
  }

  const int r0 = brow * 128 + wr * 64 + (lane >> 4) * 4;
  const int c0 = bcol * 128 + wc * 64 + (lane & 15);
#pragma unroll
  for (int mi = 0; mi < 4; ++mi)
#pragma unroll
    for (int ni = 0; ni < 4; ++ni)
#pragma unroll
      for (int j = 0; j < 4; ++j) {
        if constexpr (TC)
          C[(size_t)(c0 + ni * 16) * M + (r0 + mi * 16 + j)] = (OutT)(acc[mi][ni][j] * alpha);
        else
          C[(size_t)(r0 + mi * 16 + j) * N + (c0 + ni * 16)] = (OutT)(acc[mi][ni][j] * alpha);
      }
}

// ---------------------------------------------------------------- flash attention (causal GQA)
// Q: [4096, 2048] pre-scaled; K: [4096, 512]; Vt: [512][4096] (V transposed);
// AO: [4096, 2048]. Block: 128 q rows (4 waves x 32). KVBLK = 64.
__global__ __launch_bounds__(256)
void attn_fwd(const bf16* __restrict__ Q, const bf16* __restrict__ Kg_,
              const bf16* __restrict__ Vt, bf16* __restrict__ AO) {
  const int T = 2048, C = 2048, KVD = 512, MTOK = 4096;
  // snake mapping for causal load balance: CU pair (qt_hi, qt_lo) sums constant
  const int bid = blockIdx.x;
  const int qt  = (bid < 256) ? (15 - (bid >> 5)) : ((bid >> 5) - 8);
  const int sub = bid & 31;
  const int h   = sub & 15, b = sub >> 4;
  const int kvh = h >> 2;
  const int lane = threadIdx.x & 63, w = threadIdx.x >> 6;

  __shared__ __align__(16) char sK[64 * 256];    // [64][128] bf16, XOR swizzle (r&7)<<4
  __shared__ __align__(16) char sVt[128 * 128];  // [128 d][64 kv] bf16, XOR swizzle (d&7)<<4
  __shared__ __align__(16) bf16 sP[4][32][72];   // per-wave P, pitch 72 (36 banks)

  const bf16* Qg = Q   + (size_t)b * T * C + (size_t)h * 128;
  const bf16* Kg = Kg_ + (size_t)b * T * KVD + (size_t)kvh * 128;
  const bf16* Vg = Vt  + (size_t)kvh * 128 * MTOK + (size_t)b * T;

  const int q0 = qt * 128;
  const int qw = q0 + w * 32;

  bf16x8 qf[2][4];
#pragma unroll
  for (int m = 0; m < 2; ++m)
#pragma unroll
    for (int kk = 0; kk < 4; ++kk)
      qf[m][kk] = *(const bf16x8*)(Qg + (size_t)(qw + m * 16 + (lane & 15)) * C + kk * 32 + (lane >> 4) * 8);

  f32x4 o[2][8] = {};
  float mstat[2][4], lstat[2][4];
#pragma unroll
  for (int m = 0; m < 2; ++m)
#pragma unroll
    for (int j = 0; j < 4; ++j) { mstat[m][j] = -INFINITY; lstat[m][j] = 0.f; }

  const int ntiles = 2 * (qt + 1);
  for (int t = 0; t < ntiles; ++t) {
    const int kv0 = t * 64;
    // ---- stage K[64][128] and Vt[128][64], linear LDS dest + pre-swizzled global src
#pragma unroll
    for (int i = 0; i < 4; ++i) {
      const int ci = i * 256 + threadIdx.x;          // 16B-chunk index
      const int rk = ci >> 4, ck = ci & 15;          // K: row, chunk
      gload_lds16(Kg + (size_t)(kv0 + rk) * KVD + ((ck ^ (rk & 7)) * 8),
                  sK + (i * 4096 + w * 1024));
      const int rv = ci >> 3, cv = ci & 7;           // Vt: row(d), chunk
      gload_lds16(Vg + (size_t)rv * MTOK + kv0 + ((cv ^ (rv & 7)) * 8),
                  sVt + (i * 4096 + w * 1024));
    }
    __syncthreads();

    if (kv0 <= qw + 31) {
      // ---- QK^T : S[32 q][64 kv]
      f32x4 s_[2][4] = {};
#pragma unroll
      for (int kk = 0; kk < 4; ++kk) {
        bf16x8 kf[4];
#pragma unroll
        for (int n = 0; n < 4; ++n) {
          const int r = n * 16 + (lane & 15);
          kf[n] = *(const bf16x8*)(sK + (r * 256 + ((kk * 64 + (lane >> 4) * 16) ^ ((r & 7) << 4))));
        }
#pragma unroll
        for (int m = 0; m < 2; ++m)
#pragma unroll
          for (int n = 0; n < 4; ++n)
            s_[m][n] = __builtin_amdgcn_mfma_f32_16x16x32_bf16(qf[m][kk], kf[n], s_[m][n], 0, 0, 0);
      }
      // ---- causal mask (diagonal tiles only)
      if (kv0 + 63 > qw) {
#pragma unroll
        for (int m = 0; m < 2; ++m)
#pragma unroll
          for (int n = 0; n < 4; ++n)
#pragma unroll
            for (int j = 0; j < 4; ++j) {
              const int qr = qw + m * 16 + (lane >> 4) * 4 + j;
              const int kc = kv0 + n * 16 + (lane & 15);
              if (kc > qr) s_[m][n][j] = -1e30f;
            }
      }
      // ---- online softmax (row = m*16 + (lane>>4)*4 + j)
#pragma unroll
      for (int m = 0; m < 2; ++m)
#pragma unroll
        for (int j = 0; j < 4; ++j) {
          float pm = fmaxf(fmaxf(s_[m][0][j], s_[m][1][j]), fmaxf(s_[m][2][j], s_[m][3][j]));
          pm = fmaxf(pm, __shfl_xor(pm, 1));
          pm = fmaxf(pm, __shfl_xor(pm, 2));
          pm = fmaxf(pm, __shfl_xor(pm, 4));
          pm = fmaxf(pm, __shfl_xor(pm, 8));
          const float mn = fmaxf(mstat[m][j], pm);
          const float rs = __expf(mstat[m][j] - mn);
          mstat[m][j] = mn;
          float ls = 0.f;
#pragma unroll
          for (int n = 0; n < 4; ++n) {
            const float p = __expf(s_[m][n][j] - mn);
            s_[m][n][j] = p;
            ls += p;
          }
          ls += __shfl_xor(ls, 1);
          ls += __shfl_xor(ls, 2);
          ls += __shfl_xor(ls, 4);
          ls += __shfl_xor(ls, 8);
          lstat[m][j] = lstat[m][j] * rs + ls;
#pragma unroll
          for (int n = 0; n < 8; ++n) o[m][n][j] *= rs;
        }
      // ---- P -> LDS (D layout), reread as A fragments
#pragma unroll
      for (int m = 0; m < 2; ++m)
#pragma unroll
        for (int n = 0; n < 4; ++n)
#pragma unroll
          for (int j = 0; j < 4; ++j)
            sP[w][m * 16 + (lane >> 4) * 4 + j][n * 16 + (lane & 15)] = (bf16)s_[m][n][j];

#pragma unroll
      for (int kk2 = 0; kk2 < 2; ++kk2) {
        bf16x8 pa[2];
#pragma unroll
        for (int m = 0; m < 2; ++m)
          pa[m] = *(const bf16x8*)&sP[w][m * 16 + (lane & 15)][kk2 * 32 + (lane >> 4) * 8];
#pragma unroll
        for (int n = 0; n < 8; ++n) {
          const int rd = n * 16 + (lane & 15);
          bf16x8 vb = *(const bf16x8*)(sVt + (rd * 128 + ((kk2 * 64 + (lane >> 4) * 16) ^ ((rd & 7) << 4))));
#pragma unroll
          for (int m = 0; m < 2; ++m)
            o[m][n] = __builtin_amdgcn_mfma_f32_16x16x32_bf16(pa[m], vb, o[m][n], 0, 0, 0);
        }
      }
    }
    __syncthreads();
  }

  // ---- epilogue
  bf16* Og = AO + (size_t)b * T * C + (size_t)h * 128;
#pragma unroll
  for (int m = 0; m < 2; ++m)
#pragma unroll
    for (int j = 0; j < 4; ++j) {
      const float inv = 1.f / lstat[m][j];
      const int qr = qw + m * 16 + (lane >> 4) * 4 + j;
#pragma unroll
      for (int n = 0; n < 8; ++n)
        Og[(size_t)qr * C + n * 16 + (lane & 15)] = (bf16)(o[m][n][j] * inv);
    }
}

// ---------------------------------------------------------------- launch
extern "C" void kernel_launch(void* const* d_in, const int* in_sizes, int n_in,
                              void* d_out, int out_size, void* d_ws, size_t ws_size,
                              hipStream_t stream) {
  const int B = 2, T = 2048, C = 2048, KVD = 512;
  const int M = B * T;  // 4096

  const float* x  = (const float*)d_in[0];
  const float* Wq = (const float*)d_in[1];
  const float* Wk = (const float*)d_in[2];
  const float* Wv = (const float*)d_in[3];
  const float* Wo = (const float*)d_in[4];
  float* out = (float*)d_out;

  char* ws = (char*)d_ws;
  bf16* xb  = (bf16*)(ws);                    // 16,777,216 B
  bf16* wqb = (bf16*)(ws + 16777216);         //  8,388,608
  bf16* wkb = (bf16*)(ws + 25165824);         //  2,097,152
  bf16* wvb = (bf16*)(ws + 27262976);         //  2,097,152
  bf16* wob = (bf16*)(ws + 29360128);         //  8,388,608
  bf16* Qb  = (bf16*)(ws + 37748736);         // 16,777,216
  bf16* Kb  = (bf16*)(ws + 54525952);         //  4,194,304
  bf16* Vtb = (bf16*)(ws + 58720256);         //  4,194,304  ([512][4096])
  bf16* AOb = (bf16*)(ws + 62914560);         // 16,777,216  (end 79,691,776)

  auto conv = [&](const float* src, bf16* dst, int n) {
    int blocks = (n / 4 + 255) / 256;
    if (blocks > 2048) blocks = 2048;
    cvt_f32_bf16<<<blocks, 256, 0, stream>>>(src, dst, n);
  };
  conv(x,  xb,  M * C);
  conv(Wq, wqb, C * C);
  conv(Wk, wkb, KVD * C);
  conv(Wv, wvb, KVD * C);
  conv(Wo, wob, C * C);

  const float scale = 0.08838834764831845f;  // 128^-0.5, folded into Q
  gemm_nt<bf16, false><<<dim3(C / 128, M / 128), 256, 0, stream>>>(xb, wqb, Qb, M, C, C, scale);
  gemm_nt<bf16, false><<<dim3(KVD / 128, M / 128), 256, 0, stream>>>(xb, wkb, Kb, M, KVD, C, 1.0f);
  gemm_nt<bf16, true ><<<dim3(KVD / 128, M / 128), 256, 0, stream>>>(xb, wvb, Vtb, M, KVD, C, 1.0f);

  attn_fwd<<<512, 256, 0, stream>>>(Qb, Kb, Vtb, AOb);

  gemm_nt<float, false><<<dim3(C / 128, M / 128), 256, 0, stream>>>(AOb, wob, out, M, C, C, 1.0f);
}

// Round 3
// 324.926 us; speedup vs baseline: 1.6079x; 1.1166x over previous
//
#include <hip/hip_runtime.h>
#include <hip/hip_bf16.h>
#include <math.h>

typedef __bf16 bf16;
typedef __bf16 bf16x4 __attribute__((ext_vector_type(4)));
typedef __bf16 bf16x8 __attribute__((ext_vector_type(8)));
typedef float f32x4 __attribute__((ext_vector_type(4)));

// ---------------------------------------------------------------- helpers
__device__ __forceinline__ void gload_lds16(const void* g, void* l) {
  __builtin_amdgcn_global_load_lds(
      (const __attribute__((address_space(1))) void*)g,
      (__attribute__((address_space(3))) void*)l, 16, 0, 0);
}

// ---------------------------------------------------------------- f32 -> bf16
__global__ void cvt_f32_bf16(const float* __restrict__ in, bf16* __restrict__ out, int n) {
  int stride = gridDim.x * blockDim.x;
  for (int i = blockIdx.x * blockDim.x + threadIdx.x; i * 4 < n; i += stride) {
    float4 v = *(const float4*)(in + (size_t)i * 4);
    bf16x4 o;
    o[0] = (bf16)v.x; o[1] = (bf16)v.y; o[2] = (bf16)v.z; o[3] = (bf16)v.w;
    *(bf16x4*)(out + (size_t)i * 4) = o;
  }
}

// ---------------------------------------------------------------- NT GEMM
// C[M,N] = alpha * A[M,K] @ B[N,K]^T ; TC=true stores C^T ([N][M])
template <typename OutT, bool TC>
__global__ __launch_bounds__(256)
void gemm_nt(const bf16* __restrict__ A, const bf16* __restrict__ B,
             OutT* __restrict__ C, int M, int N, int K, float alpha) {
  __shared__ __align__(16) char smem[16384];

  const int lane = threadIdx.x & 63;
  const int w    = threadIdx.x >> 6;
  const int wr   = w >> 1, wc = w & 1;
  const int brow = blockIdx.y, bcol = blockIdx.x;

  f32x4 acc[4][4] = {};

  const bf16* Ab = A + (size_t)brow * 128 * K;
  const bf16* Bb = B + (size_t)bcol * 128 * K;

  const int srow = w * 32 + (lane >> 2);
  const int skc  = (lane & 3) * 8;

  for (int k0 = 0; k0 < K; k0 += 32) {
    gload_lds16(Ab + (size_t)srow * K + k0 + skc,        smem + w * 2048);
    gload_lds16(Ab + (size_t)(srow + 16) * K + k0 + skc, smem + w * 2048 + 1024);
    gload_lds16(Bb + (size_t)srow * K + k0 + skc,        smem + 8192 + w * 2048);
    gload_lds16(Bb + (size_t)(srow + 16) * K + k0 + skc, smem + 8192 + w * 2048 + 1024);
    __syncthreads();

    bf16x8 af[4], bfr[4];
#pragma unroll
    for (int i = 0; i < 4; ++i) {
      af[i]  = *(const bf16x8*)(smem + ((wr * 64 + i * 16 + (lane & 15)) * 64 + (lane >> 4) * 16));
      bfr[i] = *(const bf16x8*)(smem + 8192 + ((wc * 64 + i * 16 + (lane & 15)) * 64 + (lane >> 4) * 16));
    }
#pragma unroll
    for (int mi = 0; mi < 4; ++mi)
#pragma unroll
      for (int ni = 0; ni < 4; ++ni)
        acc[mi][ni] = __builtin_amdgcn_mfma_f32_16x16x32_bf16(af[mi], bfr[ni], acc[mi][ni], 0, 0, 0);
    __syncthreads();
  }

  const int r0 = brow * 128 + wr * 64 + (lane >> 4) * 4;
  const int c0 = bcol * 128 + wc * 64 + (lane & 15);
#pragma unroll
  for (int mi = 0; mi < 4; ++mi)
#pragma unroll
    for (int ni = 0; ni < 4; ++ni)
#pragma unroll
      for (int j = 0; j < 4; ++j) {
        if constexpr (TC)
          C[(size_t)(c0 + ni * 16) * M + (r0 + mi * 16 + j)] = (OutT)(acc[mi][ni][j] * alpha);
        else
          C[(size_t)(r0 + mi * 16 + j) * N + (c0 + ni * 16)] = (OutT)(acc[mi][ni][j] * alpha);
      }
}

// ---------------------------------------------------------------- flash attention (causal GQA)
// Q: [4096,2048] pre-scaled; K: [4096,512]; Vt: [512][4096]; AO: [4096,2048].
// Block: 64 q rows (4 waves x 16). KVBLK=64, double-buffered, counted-vmcnt prefetch.
__global__ __launch_bounds__(256)
void attn_fwd(const bf16* __restrict__ Q, const bf16* __restrict__ Kg_,
              const bf16* __restrict__ Vt, bf16* __restrict__ AO) {
  const int T = 2048, C = 2048, KVD = 512, MTOK = 4096;
  // 4-chunk balanced qt map: per-slot sum over chunks = 62 (const)
  const int bid = blockIdx.x;
  const int c = bid >> 8, s = bid & 255;
  const int slot = s >> 5, bh = s & 31;
  const int qt = (c == 0) ? 31 - slot : (c == 1) ? slot : (c == 2) ? 23 - slot : 8 + slot;
  const int h = bh & 15, b = bh >> 4;
  const int kvh = h >> 2;
  const int lane = threadIdx.x & 63, w = threadIdx.x >> 6;

  __shared__ __align__(16) char sK[2][16384];   // [64][128] bf16, chunk-XOR swizzle
  __shared__ __align__(16) char sVt[2][16384];  // [128][64] bf16, chunk-XOR swizzle
  __shared__ __align__(16) bf16 sP[4][16][72];  // per-wave P

  const bf16* Qg = Q   + (size_t)b * T * C + (size_t)h * 128;
  const bf16* Kg = Kg_ + (size_t)b * T * KVD + (size_t)kvh * 128;
  const bf16* Vg = Vt  + (size_t)kvh * 128 * MTOK + (size_t)b * T;

  const int q0 = qt * 64;
  const int qw = q0 + w * 16;

  bf16x8 qf[4];
#pragma unroll
  for (int kk = 0; kk < 4; ++kk)
    qf[kk] = *(const bf16x8*)(Qg + (size_t)(qw + (lane & 15)) * C + kk * 32 + (lane >> 4) * 8);

  f32x4 o[8] = {};
  float mstat[4], lstat[4];
#pragma unroll
  for (int j = 0; j < 4; ++j) { mstat[j] = -INFINITY; lstat[j] = 0.f; }

  const int nt = qt + 1;

  auto stage = [&](int t, int buf) {
#pragma unroll
    for (int i = 0; i < 4; ++i) {
      const int ci = i * 256 + threadIdx.x;
      const int rk = ci >> 4, ck = ci & 15;
      gload_lds16(Kg + (size_t)(t * 64 + rk) * KVD + ((ck ^ (rk & 7)) * 8),
                  &sK[buf][i * 4096 + w * 1024]);
      const int rv = ci >> 3, cv = ci & 7;
      gload_lds16(Vg + (size_t)rv * MTOK + t * 64 + ((cv ^ (rv & 7)) * 8),
                  &sVt[buf][i * 4096 + w * 1024]);
    }
  };

  auto compute = [&](int t, int buf) {
    const int kv0 = t * 64;
    if (kv0 > qw + 15) return;  // wave-uniform causal skip (no barriers inside)
    f32x4 s_[4] = {};
#pragma unroll
    for (int kk = 0; kk < 4; ++kk) {
      bf16x8 kf[4];
#pragma unroll
      for (int n = 0; n < 4; ++n) {
        const int r = n * 16 + (lane & 15);
        kf[n] = *(const bf16x8*)(&sK[buf][0] + (r * 256 + ((kk * 64 + (lane >> 4) * 16) ^ ((r & 7) << 4))));
      }
#pragma unroll
      for (int n = 0; n < 4; ++n)
        s_[n] = __builtin_amdgcn_mfma_f32_16x16x32_bf16(qf[kk], kf[n], s_[n], 0, 0, 0);
    }
    if (kv0 + 63 > qw) {
#pragma unroll
      for (int n = 0; n < 4; ++n)
#pragma unroll
        for (int j = 0; j < 4; ++j) {
          const int qr = qw + (lane >> 4) * 4 + j;
          const int kc = kv0 + n * 16 + (lane & 15);
          if (kc > qr) s_[n][j] = -1e30f;
        }
    }
    // row maxes
    float pm[4];
#pragma unroll
    for (int j = 0; j < 4; ++j) {
      float v = fmaxf(fmaxf(s_[0][j], s_[1][j]), fmaxf(s_[2][j], s_[3][j]));
      v = fmaxf(v, __shfl_xor(v, 1));
      v = fmaxf(v, __shfl_xor(v, 2));
      v = fmaxf(v, __shfl_xor(v, 4));
      v = fmaxf(v, __shfl_xor(v, 8));
      pm[j] = v;
    }
    // defer-max: rescale only when a row's max grew past threshold
    bool need = false;
#pragma unroll
    for (int j = 0; j < 4; ++j) need = need || (pm[j] > mstat[j] + 8.f);
    if (__any(need)) {
#pragma unroll
      for (int j = 0; j < 4; ++j) {
        const float mn = fmaxf(mstat[j], pm[j]);
        const float rs = __expf(mstat[j] - mn);
        mstat[j] = mn;
        lstat[j] *= rs;
#pragma unroll
        for (int n = 0; n < 8; ++n) o[n][j] *= rs;
      }
    }
    float ls[4] = {0.f, 0.f, 0.f, 0.f};
#pragma unroll
    for (int n = 0; n < 4; ++n)
#pragma unroll
      for (int j = 0; j < 4; ++j) {
        const float p = __expf(s_[n][j] - mstat[j]);
        s_[n][j] = p;
        ls[j] += p;
      }
#pragma unroll
    for (int j = 0; j < 4; ++j) {
      float v = ls[j];
      v += __shfl_xor(v, 1);
      v += __shfl_xor(v, 2);
      v += __shfl_xor(v, 4);
      v += __shfl_xor(v, 8);
      lstat[j] += v;
    }
    // P -> LDS (D layout), reread as A fragments (per-wave buffer, no barrier)
#pragma unroll
    for (int n = 0; n < 4; ++n)
#pragma unroll
      for (int j = 0; j < 4; ++j)
        sP[w][(lane >> 4) * 4 + j][n * 16 + (lane & 15)] = (bf16)s_[n][j];

#pragma unroll
    for (int kk2 = 0; kk2 < 2; ++kk2) {
      bf16x8 pa = *(const bf16x8*)&sP[w][lane & 15][kk2 * 32 + (lane >> 4) * 8];
#pragma unroll
      for (int n = 0; n < 8; ++n) {
        const int rd = n * 16 + (lane & 15);
        bf16x8 vb = *(const bf16x8*)(&sVt[buf][0] + (rd * 128 + ((kk2 * 64 + (lane >> 4) * 16) ^ ((rd & 7) << 4))));
        o[n] = __builtin_amdgcn_mfma_f32_16x16x32_bf16(pa, vb, o[n], 0, 0, 0);
      }
    }
  };

  stage(0, 0);
  for (int t = 0; t < nt - 1; ++t) {
    stage(t + 1, (t + 1) & 1);
    asm volatile("s_waitcnt vmcnt(8)" ::: "memory");  // older 8 (tile t) done; 8 newer in flight
    __builtin_amdgcn_s_barrier();
    compute(t, t & 1);
    __builtin_amdgcn_s_barrier();
  }
  asm volatile("s_waitcnt vmcnt(0)" ::: "memory");
  __builtin_amdgcn_s_barrier();
  compute(nt - 1, (nt - 1) & 1);

  bf16* Og = AO + (size_t)b * T * C + (size_t)h * 128;
#pragma unroll
  for (int j = 0; j < 4; ++j) {
    const float inv = 1.f / lstat[j];
    const int qr = qw + (lane >> 4) * 4 + j;
#pragma unroll
    for (int n = 0; n < 8; ++n)
      Og[(size_t)qr * C + n * 16 + (lane & 15)] = (bf16)(o[n][j] * inv);
  }
}

// ---------------------------------------------------------------- launch
extern "C" void kernel_launch(void* const* d_in, const int* in_sizes, int n_in,
                              void* d_out, int out_size, void* d_ws, size_t ws_size,
                              hipStream_t stream) {
  const int B = 2, T = 2048, C = 2048, KVD = 512;
  const int M = B * T;  // 4096

  const float* x  = (const float*)d_in[0];
  const float* Wq = (const float*)d_in[1];
  const float* Wk = (const float*)d_in[2];
  const float* Wv = (const float*)d_in[3];
  const float* Wo = (const float*)d_in[4];
  float* out = (float*)d_out;

  char* ws = (char*)d_ws;
  bf16* xb  = (bf16*)(ws);                    // 16,777,216 B
  bf16* wqb = (bf16*)(ws + 16777216);         //  8,388,608
  bf16* wkb = (bf16*)(ws + 25165824);         //  2,097,152
  bf16* wvb = (bf16*)(ws + 27262976);         //  2,097,152
  bf16* wob = (bf16*)(ws + 29360128);         //  8,388,608
  bf16* Qb  = (bf16*)(ws + 37748736);         // 16,777,216
  bf16* Kb  = (bf16*)(ws + 54525952);         //  4,194,304
  bf16* Vtb = (bf16*)(ws + 58720256);         //  4,194,304  ([512][4096])
  bf16* AOb = (bf16*)(ws + 62914560);         // 16,777,216

  auto conv = [&](const float* src, bf16* dst, int n) {
    int blocks = (n / 4 + 255) / 256;
    if (blocks > 2048) blocks = 2048;
    cvt_f32_bf16<<<blocks, 256, 0, stream>>>(src, dst, n);
  };
  conv(x,  xb,  M * C);
  conv(Wq, wqb, C * C);
  conv(Wk, wkb, KVD * C);
  conv(Wv, wvb, KVD * C);
  conv(Wo, wob, C * C);

  const float scale = 0.08838834764831845f;  // 128^-0.5, folded into Q
  gemm_nt<bf16, false><<<dim3(C / 128, M / 128), 256, 0, stream>>>(xb, wqb, Qb, M, C, C, scale);
  gemm_nt<bf16, false><<<dim3(KVD / 128, M / 128), 256, 0, stream>>>(xb, wkb, Kb, M, KVD, C, 1.0f);
  gemm_nt<bf16, true ><<<dim3(KVD / 128, M / 128), 256, 0, stream>>>(xb, wvb, Vtb, M, KVD, C, 1.0f);

  attn_fwd<<<1024, 256, 0, stream>>>(Qb, Kb, Vtb, AOb);

  gemm_nt<float, false><<<dim3(C / 128, M / 128), 256, 0, stream>>>(AOb, wob, out, M, C, C, 1.0f);
}

// Round 4
// 282.782 us; speedup vs baseline: 1.8476x; 1.1490x over previous
//
#include <hip/hip_runtime.h>
#include <hip/hip_bf16.h>
#include <math.h>

typedef __bf16 bf16;
typedef __bf16 bf16x4 __attribute__((ext_vector_type(4)));
typedef __bf16 bf16x8 __attribute__((ext_vector_type(8)));
typedef float f32x4 __attribute__((ext_vector_type(4)));
typedef float f32x16 __attribute__((ext_vector_type(16)));
typedef unsigned int uint32x4 __attribute__((ext_vector_type(4)));

// ---------------------------------------------------------------- helpers
__device__ __forceinline__ void gload_lds16(const void* g, void* l) {
  __builtin_amdgcn_global_load_lds(
      (const __attribute__((address_space(1))) void*)g,
      (__attribute__((address_space(3))) void*)l, 16, 0, 0);
}

__device__ __forceinline__ unsigned int packbf(float a, float b) {
  union { bf16 h[2]; unsigned int u; } x;
  x.h[0] = (bf16)a; x.h[1] = (bf16)b;
  return x.u;
}

// ---------------------------------------------------------------- f32 -> bf16
__global__ void cvt_f32_bf16(const float* __restrict__ in, bf16* __restrict__ out, int n) {
  int stride = gridDim.x * blockDim.x;
  for (int i = blockIdx.x * blockDim.x + threadIdx.x; i * 4 < n; i += stride) {
    float4 v = *(const float4*)(in + (size_t)i * 4);
    bf16x4 o;
    o[0] = (bf16)v.x; o[1] = (bf16)v.y; o[2] = (bf16)v.z; o[3] = (bf16)v.w;
    *(bf16x4*)(out + (size_t)i * 4) = o;
  }
}

// ---------------------------------------------------------------- NT GEMM (m97 structure)
template <typename OutT, bool TC>
__global__ __launch_bounds__(256)
void gemm_nt(const bf16* __restrict__ A, const bf16* __restrict__ B,
             OutT* __restrict__ C, int M, int N, int K, float alpha) {
  __shared__ __align__(16) char smem[16384];

  const int lane = threadIdx.x & 63;
  const int w    = threadIdx.x >> 6;
  const int wr   = w >> 1, wc = w & 1;
  const int brow = blockIdx.y, bcol = blockIdx.x;

  f32x4 acc[4][4] = {};

  const bf16* Ab = A + (size_t)brow * 128 * K;
  const bf16* Bb = B + (size_t)bcol * 128 * K;

  const int srow = w * 32 + (lane >> 2);
  const int skc  = (lane & 3) * 8;

  for (int k0 = 0; k0 < K; k0 += 32) {
    gload_lds16(Ab + (size_t)srow * K + k0 + skc,        smem + w * 2048);
    gload_lds16(Ab + (size_t)(srow + 16) * K + k0 + skc, smem + w * 2048 + 1024);
    gload_lds16(Bb + (size_t)srow * K + k0 + skc,        smem + 8192 + w * 2048);
    gload_lds16(Bb + (size_t)(srow + 16) * K + k0 + skc, smem + 8192 + w * 2048 + 1024);
    __syncthreads();

    bf16x8 af[4], bfr[4];
#pragma unroll
    for (int i = 0; i < 4; ++i) {
      af[i]  = *(const bf16x8*)(smem + ((wr * 64 + i * 16 + (lane & 15)) * 64 + (lane >> 4) * 16));
      bfr[i] = *(const bf16x8*)(smem + 8192 + ((wc * 64 + i * 16 + (lane & 15)) * 64 + (lane >> 4) * 16));
    }
#pragma unroll
    for (int mi = 0; mi < 4; ++mi)
#pragma unroll
      for (int ni = 0; ni < 4; ++ni)
        acc[mi][ni] = __builtin_amdgcn_mfma_f32_16x16x32_bf16(af[mi], bfr[ni], acc[mi][ni], 0, 0, 0);
    __syncthreads();
  }

  const int r0 = brow * 128 + wr * 64 + (lane >> 4) * 4;
  const int c0 = bcol * 128 + wc * 64 + (lane & 15);
#pragma unroll
  for (int mi = 0; mi < 4; ++mi)
#pragma unroll
    for (int ni = 0; ni < 4; ++ni)
#pragma unroll
      for (int j = 0; j < 4; ++j) {
        if constexpr (TC)
          C[(size_t)(c0 + ni * 16) * M + (r0 + mi * 16 + j)] = (OutT)(acc[mi][ni][j] * alpha);
        else
          C[(size_t)(r0 + mi * 16 + j) * N + (c0 + ni * 16)] = (OutT)(acc[mi][ni][j] * alpha);
      }
}

// ---------------------------------------------------------------- flash attention (causal GQA)
// 32x32 MFMA, swapped operands: S^T = K*Q^T (lane owns q=lane&31), O^T = V^T*P^T.
// Q: [4096,2048] pre-scaled; K: [4096,512]; Vt: [512][4096]; AO: [4096,2048].
// Block: 128 q rows (4 waves x 32). KVBLK=64, dbuf, counted-vmcnt prefetch.
__global__ __launch_bounds__(256, 2)
void attn_fwd(const bf16* __restrict__ Q, const bf16* __restrict__ Kg_,
              const bf16* __restrict__ Vt, bf16* __restrict__ AO) {
  const int T = 2048, C = 2048, KVD = 512, MTOK = 4096;
  const int bid = blockIdx.x;
  const int qt  = (bid < 256) ? (15 - (bid >> 5)) : ((bid >> 5) - 8);  // snake balance
  const int sub = bid & 31;
  const int h = sub & 15, b = sub >> 4;
  const int kvh = h >> 2;
  const int lane = threadIdx.x & 63, w = threadIdx.x >> 6;
  const int hi = lane >> 5, lo = lane & 31;

  __shared__ __align__(16) char smem[65536];
  char* sK  = smem;          // 2 bufs x [64 rows][256 B], chunk-XOR (r&7)
  char* sVt = smem + 32768;  // 2 bufs x [128 rows][128 B], chunk-XOR (r&7)

  const bf16* Qg = Q   + (size_t)b * T * C + (size_t)h * 128;
  const bf16* Kg = Kg_ + (size_t)b * T * KVD + (size_t)kvh * 128;
  const bf16* Vg = Vt  + (size_t)kvh * 128 * MTOK + (size_t)b * T;

  const int q0 = qt * 128;
  const int qw = q0 + w * 32;   // wave's first q row; lane's q = qw + lo

  // Q as B-fragments: lane holds Q[qw+lo][ks*16 + hi*8 .. +7]
  bf16x8 qf[8];
#pragma unroll
  for (int ks = 0; ks < 8; ++ks)
    qf[ks] = *(const bf16x8*)(Qg + (size_t)(qw + lo) * C + ks * 16 + hi * 8);

  f32x16 ot[4] = {};            // O^T acc: d = db*32 + (r&3)+8*(r>>2)+4*hi, q = lo
  float mstat = -INFINITY, lstat = 0.f;

  const int nt = 2 * qt + 2;

  auto stage = [&](int t, int buf) {
#pragma unroll
    for (int i = 0; i < 4; ++i) {
      const int ci = i * 256 + threadIdx.x;
      const int rk = ci >> 4, ck = ci & 15;   // K: 64 rows x 16 chunks
      gload_lds16(Kg + (size_t)(t * 64 + rk) * KVD + ((ck ^ (rk & 7)) * 8),
                  sK + buf * 16384 + i * 4096 + w * 1024);
      const int rv = ci >> 3, cv = ci & 7;    // Vt: 128 rows x 8 chunks
      gload_lds16(Vg + (size_t)rv * MTOK + t * 64 + ((cv ^ (rv & 7)) * 8),
                  sVt + buf * 16384 + i * 4096 + w * 1024);
    }
  };

  auto compute = [&](int t, int buf) {
    const int kv0 = t * 64;
    if (kv0 > qw + 31) return;               // wave-uniform causal skip
    const char* kb = sK + buf * 16384;
    const char* vb = sVt + buf * 16384;

    // ---- S^T = K * Q^T : lane holds S[q=lo][kv], kv = nb*32 + (r&3)+8*(r>>2)+4*hi
    f32x16 sa[2] = {};
#pragma unroll
    for (int ks = 0; ks < 8; ++ks) {
#pragma unroll
      for (int nb = 0; nb < 2; ++nb) {
        const int r = nb * 32 + lo;
        bf16x8 kf = *(const bf16x8*)(kb + (r * 256 + (((ks * 2 + hi) ^ (r & 7)) * 16)));
        sa[nb] = __builtin_amdgcn_mfma_f32_32x32x16_bf16(kf, qf[ks], sa[nb], 0, 0, 0);
      }
    }
    // ---- causal mask (diagonal-straddling tiles only)
    if (kv0 + 63 > qw) {
      const int qg = qw + lo;
#pragma unroll
      for (int nb = 0; nb < 2; ++nb)
#pragma unroll
        for (int r = 0; r < 16; ++r) {
          const int kvg = kv0 + nb * 32 + (r & 3) + 8 * (r >> 2) + 4 * hi;
          if (kvg > qg) sa[nb][r] = -1e30f;
        }
    }
    // ---- lane-local online softmax
    float pm = -INFINITY;
#pragma unroll
    for (int nb = 0; nb < 2; ++nb)
#pragma unroll
      for (int r = 0; r < 16; ++r) pm = fmaxf(pm, sa[nb][r]);
    pm = fmaxf(pm, __shfl_xor(pm, 32));

    if (__any(pm > mstat + 8.f)) {           // defer-max (T13)
      const float mn = fmaxf(mstat, pm);
      const float rs = __expf(mstat - mn);
      mstat = mn;
      lstat *= rs;
#pragma unroll
      for (int db = 0; db < 4; ++db)
#pragma unroll
        for (int r = 0; r < 16; ++r) ot[db][r] *= rs;
    }

    float ls = 0.f;
    unsigned int pw[2][8];
#pragma unroll
    for (int nb = 0; nb < 2; ++nb)
#pragma unroll
      for (int j = 0; j < 8; ++j) {
        const float e0 = __expf(sa[nb][2 * j]     - mstat);
        const float e1 = __expf(sa[nb][2 * j + 1] - mstat);
        ls += e0 + e1;
        pw[nb][j] = packbf(e0, e1);
      }
    ls += __shfl_xor(ls, 32);
    lstat += ls;

    // ---- O^T += V^T * P^T
#pragma unroll
    for (int nb = 0; nb < 2; ++nb) {
      unsigned int pj[8];
#pragma unroll
      for (int j = 0; j < 8; ++j) pj[j] = __shfl_xor(pw[nb][j], 32);
#pragma unroll
      for (int half = 0; half < 2; ++half) {
        const int x = half * 4;
        uint32x4 bw;
        bw[0] = hi ? pj[x + 2] : pw[nb][x + 0];
        bw[1] = hi ? pj[x + 3] : pw[nb][x + 1];
        bw[2] = hi ? pw[nb][x + 2] : pj[x + 0];
        bw[3] = hi ? pw[nb][x + 3] : pj[x + 1];
        const bf16x8 pb = __builtin_bit_cast(bf16x8, bw);
        const int ks = nb * 2 + half;        // kv 16-step within 64-tile
#pragma unroll
        for (int db = 0; db < 4; ++db) {
          const int rv = db * 32 + lo;
          bf16x8 vf = *(const bf16x8*)(vb + (rv * 128 + (((ks * 2 + hi) ^ (rv & 7)) * 16)));
          ot[db] = __builtin_amdgcn_mfma_f32_32x32x16_bf16(vf, pb, ot[db], 0, 0, 0);
        }
      }
    }
  };

  stage(0, 0);
  for (int t = 0; t < nt - 1; ++t) {
    stage(t + 1, (t + 1) & 1);
    asm volatile("s_waitcnt vmcnt(8)" ::: "memory");
    __builtin_amdgcn_s_barrier();
    compute(t, t & 1);
    __builtin_amdgcn_s_barrier();
  }
  asm volatile("s_waitcnt vmcnt(0)" ::: "memory");
  __builtin_amdgcn_s_barrier();
  compute(nt - 1, (nt - 1) & 1);

  // ---- epilogue: O^T -> LDS (reuse sK region) -> coalesced global store
  __syncthreads();
  char* sO = smem;                            // [128 q][256 B], XOR (q&7)<<4
  const float inv = 1.f / lstat;
  const int lq = w * 32 + lo;
#pragma unroll
  for (int db = 0; db < 4; ++db) {
#pragma unroll
    for (int j = 0; j < 8; ++j) {
      const int r = 2 * j;
      const int d = db * 32 + (r & 3) + 8 * (r >> 2) + 4 * hi;
      const unsigned int pv = packbf(ot[db][r] * inv, ot[db][r + 1] * inv);
      *(unsigned int*)(sO + (lq * 256 + ((2 * d) ^ (16 * (lq & 7))))) = pv;
    }
  }
  __syncthreads();
  bf16* Og = AO + (size_t)b * T * C + (size_t)h * 128;
#pragma unroll
  for (int i = 0; i < 8; ++i) {
    const int cid = i * 256 + threadIdx.x;
    const int rq = cid >> 4, c = cid & 15;
    bf16x8 vv = *(const bf16x8*)(sO + (rq * 256 + ((c * 16) ^ (16 * (rq & 7)))));
    *(bf16x8*)(Og + (size_t)(q0 + rq) * C + c * 8) = vv;
  }
}

// ---------------------------------------------------------------- launch
extern "C" void kernel_launch(void* const* d_in, const int* in_sizes, int n_in,
                              void* d_out, int out_size, void* d_ws, size_t ws_size,
                              hipStream_t stream) {
  const int B = 2, T = 2048, C = 2048, KVD = 512;
  const int M = B * T;  // 4096

  const float* x  = (const float*)d_in[0];
  const float* Wq = (const float*)d_in[1];
  const float* Wk = (const float*)d_in[2];
  const float* Wv = (const float*)d_in[3];
  const float* Wo = (const float*)d_in[4];
  float* out = (float*)d_out;

  char* ws = (char*)d_ws;
  bf16* xb  = (bf16*)(ws);                    // 16,777,216 B
  bf16* wqb = (bf16*)(ws + 16777216);         //  8,388,608
  bf16* wkb = (bf16*)(ws + 25165824);         //  2,097,152
  bf16* wvb = (bf16*)(ws + 27262976);         //  2,097,152
  bf16* wob = (bf16*)(ws + 29360128);         //  8,388,608
  bf16* Qb  = (bf16*)(ws + 37748736);         // 16,777,216
  bf16* Kb  = (bf16*)(ws + 54525952);         //  4,194,304
  bf16* Vtb = (bf16*)(ws + 58720256);         //  4,194,304  ([512][4096])
  bf16* AOb = (bf16*)(ws + 62914560);         // 16,777,216

  auto conv = [&](const float* src, bf16* dst, int n) {
    int blocks = (n / 4 + 255) / 256;
    if (blocks > 2048) blocks = 2048;
    cvt_f32_bf16<<<blocks, 256, 0, stream>>>(src, dst, n);
  };
  conv(x,  xb,  M * C);
  conv(Wq, wqb, C * C);
  conv(Wk, wkb, KVD * C);
  conv(Wv, wvb, KVD * C);
  conv(Wo, wob, C * C);

  const float scale = 0.08838834764831845f;  // 128^-0.5, folded into Q
  gemm_nt<bf16, false><<<dim3(C / 128, M / 128), 256, 0, stream>>>(xb, wqb, Qb, M, C, C, scale);
  gemm_nt<bf16, false><<<dim3(KVD / 128, M / 128), 256, 0, stream>>>(xb, wkb, Kb, M, KVD, C, 1.0f);
  gemm_nt<bf16, true ><<<dim3(KVD / 128, M / 128), 256, 0, stream>>>(xb, wvb, Vtb, M, KVD, C, 1.0f);

  attn_fwd<<<512, 256, 0, stream>>>(Qb, Kb, Vtb, AOb);

  gemm_nt<float, false><<<dim3(C / 128, M / 128), 256, 0, stream>>>(AOb, wob, out, M, C, C, 1.0f);
}

// Round 5
// 204.944 us; speedup vs baseline: 2.5493x; 1.3798x over previous
//
#include <hip/hip_runtime.h>
#include <hip/hip_bf16.h>
#include <math.h>

typedef __bf16 bf16;
typedef __bf16 bf16x4 __attribute__((ext_vector_type(4)));
typedef __bf16 bf16x8 __attribute__((ext_vector_type(8)));
typedef float f32x4 __attribute__((ext_vector_type(4)));
typedef float f32x16 __attribute__((ext_vector_type(16)));
typedef unsigned int uint32x4 __attribute__((ext_vector_type(4)));

// ---------------------------------------------------------------- helpers
__device__ __forceinline__ void gload_lds16(const void* g, void* l) {
  __builtin_amdgcn_global_load_lds(
      (const __attribute__((address_space(1))) void*)g,
      (__attribute__((address_space(3))) void*)l, 16, 0, 0);
}

__device__ __forceinline__ unsigned int packbf(float a, float b) {
  union { bf16 h[2]; unsigned int u; } x;
  x.h[0] = (bf16)a; x.h[1] = (bf16)b;
  return x.u;
}

// ---------------------------------------------------------------- fused f32 -> bf16 (all tensors, one launch)
// segments (f32 elems): x 8388608 | Wq 4194304 (scaled) | Wk 1048576 | Wv 1048576 | Wo 4194304
__global__ void cvt_all(const float* __restrict__ x,  const float* __restrict__ Wq,
                        const float* __restrict__ Wk, const float* __restrict__ Wv,
                        const float* __restrict__ Wo,
                        bf16* __restrict__ xb, bf16* __restrict__ wqkv, bf16* __restrict__ wob,
                        float qscale) {
  const int stride = gridDim.x * blockDim.x;
  const int total4 = 4718592;  // 18,874,368 / 4
  for (int i = blockIdx.x * blockDim.x + threadIdx.x; i < total4; i += stride) {
    const size_t e = (size_t)i * 4;
    const float* src; bf16* dst; size_t off; float sc = 1.f;
    if (e < 8388608)       { src = x;  dst = xb;            off = e; }
    else if (e < 12582912) { src = Wq; dst = wqkv;          off = e - 8388608; sc = qscale; }
    else if (e < 13631488) { src = Wk; dst = wqkv + 4194304; off = e - 12582912; }
    else if (e < 14680064) { src = Wv; dst = wqkv + 5242880; off = e - 13631488; }
    else                   { src = Wo; dst = wob;           off = e - 14680064; }
    float4 v = *(const float4*)(src + off);
    bf16x4 o;
    o[0] = (bf16)(v.x * sc); o[1] = (bf16)(v.y * sc);
    o[2] = (bf16)(v.z * sc); o[3] = (bf16)(v.w * sc);
    *(bf16x4*)(dst + off) = o;
  }
}

// ---------------------------------------------------------------- fused QKV GEMM
// [Q|K|V](4096x3072) = xb(4096x2048) @ Wqkv(3072x2048)^T, epilogue routes per bcol:
// bcol<16 -> Qb[4096][2048]; 16..19 -> Kb[4096][512]; 20..23 -> Vtb[512][4096] (transposed)
__global__ __launch_bounds__(256)
void gemm_qkv(const bf16* __restrict__ A, const bf16* __restrict__ B,
              bf16* __restrict__ Qb, bf16* __restrict__ Kb, bf16* __restrict__ Vtb) {
  const int K = 2048;
  __shared__ __align__(16) char smem[16384];

  const int lane = threadIdx.x & 63;
  const int w    = threadIdx.x >> 6;
  const int wr   = w >> 1, wc = w & 1;
  const int brow = blockIdx.y, bcol = blockIdx.x;

  f32x4 acc[4][4] = {};

  const bf16* Ab = A + (size_t)brow * 128 * K;
  const bf16* Bb = B + (size_t)bcol * 128 * K;

  const int srow = w * 32 + (lane >> 2);
  const int skc  = (lane & 3) * 8;

  for (int k0 = 0; k0 < K; k0 += 32) {
    gload_lds16(Ab + (size_t)srow * K + k0 + skc,        smem + w * 2048);
    gload_lds16(Ab + (size_t)(srow + 16) * K + k0 + skc, smem + w * 2048 + 1024);
    gload_lds16(Bb + (size_t)srow * K + k0 + skc,        smem + 8192 + w * 2048);
    gload_lds16(Bb + (size_t)(srow + 16) * K + k0 + skc, smem + 8192 + w * 2048 + 1024);
    __syncthreads();

    bf16x8 af[4], bfr[4];
#pragma unroll
    for (int i = 0; i < 4; ++i) {
      af[i]  = *(const bf16x8*)(smem + ((wr * 64 + i * 16 + (lane & 15)) * 64 + (lane >> 4) * 16));
      bfr[i] = *(const bf16x8*)(smem + 8192 + ((wc * 64 + i * 16 + (lane & 15)) * 64 + (lane >> 4) * 16));
    }
#pragma unroll
    for (int mi = 0; mi < 4; ++mi)
#pragma unroll
      for (int ni = 0; ni < 4; ++ni)
        acc[mi][ni] = __builtin_amdgcn_mfma_f32_16x16x32_bf16(af[mi], bfr[ni], acc[mi][ni], 0, 0, 0);
    __syncthreads();
  }

  const int r0 = brow * 128 + wr * 64 + (lane >> 4) * 4;
  const int c0 = bcol * 128 + wc * 64 + (lane & 15);
#pragma unroll
  for (int mi = 0; mi < 4; ++mi)
#pragma unroll
    for (int ni = 0; ni < 4; ++ni)
#pragma unroll
      for (int j = 0; j < 4; ++j) {
        const int r = r0 + mi * 16 + j, c = c0 + ni * 16;
        const bf16 v = (bf16)acc[mi][ni][j];
        if (bcol < 16)       Qb[(size_t)r * 2048 + c] = v;
        else if (bcol < 20)  Kb[(size_t)r * 512 + (c - 2048)] = v;
        else                 Vtb[(size_t)(c - 2560) * 4096 + r] = v;
      }
}

// ---------------------------------------------------------------- NT GEMM (O-proj)
__global__ __launch_bounds__(256)
void gemm_nt(const bf16* __restrict__ A, const bf16* __restrict__ B,
             float* __restrict__ C, int M, int N, int K) {
  __shared__ __align__(16) char smem[16384];

  const int lane = threadIdx.x & 63;
  const int w    = threadIdx.x >> 6;
  const int wr   = w >> 1, wc = w & 1;
  const int brow = blockIdx.y, bcol = blockIdx.x;

  f32x4 acc[4][4] = {};

  const bf16* Ab = A + (size_t)brow * 128 * K;
  const bf16* Bb = B + (size_t)bcol * 128 * K;

  const int srow = w * 32 + (lane >> 2);
  const int skc  = (lane & 3) * 8;

  for (int k0 = 0; k0 < K; k0 += 32) {
    gload_lds16(Ab + (size_t)srow * K + k0 + skc,        smem + w * 2048);
    gload_lds16(Ab + (size_t)(srow + 16) * K + k0 + skc, smem + w * 2048 + 1024);
    gload_lds16(Bb + (size_t)srow * K + k0 + skc,        smem + 8192 + w * 2048);
    gload_lds16(Bb + (size_t)(srow + 16) * K + k0 + skc, smem + 8192 + w * 2048 + 1024);
    __syncthreads();

    bf16x8 af[4], bfr[4];
#pragma unroll
    for (int i = 0; i < 4; ++i) {
      af[i]  = *(const bf16x8*)(smem + ((wr * 64 + i * 16 + (lane & 15)) * 64 + (lane >> 4) * 16));
      bfr[i] = *(const bf16x8*)(smem + 8192 + ((wc * 64 + i * 16 + (lane & 15)) * 64 + (lane >> 4) * 16));
    }
#pragma unroll
    for (int mi = 0; mi < 4; ++mi)
#pragma unroll
      for (int ni = 0; ni < 4; ++ni)
        acc[mi][ni] = __builtin_amdgcn_mfma_f32_16x16x32_bf16(af[mi], bfr[ni], acc[mi][ni], 0, 0, 0);
    __syncthreads();
  }

  const int r0 = brow * 128 + wr * 64 + (lane >> 4) * 4;
  const int c0 = bcol * 128 + wc * 64 + (lane & 15);
#pragma unroll
  for (int mi = 0; mi < 4; ++mi)
#pragma unroll
    for (int ni = 0; ni < 4; ++ni)
#pragma unroll
      for (int j = 0; j < 4; ++j)
        C[(size_t)(r0 + mi * 16 + j) * N + c0 + ni * 16] = acc[mi][ni][j];
}

// ---------------------------------------------------------------- flash attention (causal GQA)
// 32x32 MFMA, swapped operands: S^T = K*Q^T (lane owns q=lane&31), O^T = V^T*P^T.
__global__ __launch_bounds__(256, 2)
void attn_fwd(const bf16* __restrict__ Q, const bf16* __restrict__ Kg_,
              const bf16* __restrict__ Vt, bf16* __restrict__ AO) {
  const int T = 2048, C = 2048, KVD = 512, MTOK = 4096;
  const int bid = blockIdx.x;
  const int qt  = (bid < 256) ? (15 - (bid >> 5)) : ((bid >> 5) - 8);  // snake balance
  const int sub = bid & 31;
  const int h = sub & 15, b = sub >> 4;
  const int kvh = h >> 2;
  const int lane = threadIdx.x & 63, w = threadIdx.x >> 6;
  const int hi = lane >> 5, lo = lane & 31;

  __shared__ __align__(16) char smem[65536];
  char* sK  = smem;          // 2 bufs x [64 rows][256 B], chunk-XOR (r&7)
  char* sVt = smem + 32768;  // 2 bufs x [128 rows][128 B], chunk-XOR (r&7)

  const bf16* Qg = Q   + (size_t)b * T * C + (size_t)h * 128;
  const bf16* Kg = Kg_ + (size_t)b * T * KVD + (size_t)kvh * 128;
  const bf16* Vg = Vt  + (size_t)kvh * 128 * MTOK + (size_t)b * T;

  const int q0 = qt * 128;
  const int qw = q0 + w * 32;

  bf16x8 qf[8];
#pragma unroll
  for (int ks = 0; ks < 8; ++ks)
    qf[ks] = *(const bf16x8*)(Qg + (size_t)(qw + lo) * C + ks * 16 + hi * 8);

  f32x16 ot[4] = {};
  float mstat = -INFINITY, lstat = 0.f;

  const int nt = 2 * qt + 2;

  auto stage = [&](int t, int buf) {
#pragma unroll
    for (int i = 0; i < 4; ++i) {
      const int ci = i * 256 + threadIdx.x;
      const int rk = ci >> 4, ck = ci & 15;
      gload_lds16(Kg + (size_t)(t * 64 + rk) * KVD + ((ck ^ (rk & 7)) * 8),
                  sK + buf * 16384 + i * 4096 + w * 1024);
      const int rv = ci >> 3, cv = ci & 7;
      gload_lds16(Vg + (size_t)rv * MTOK + t * 64 + ((cv ^ (rv & 7)) * 8),
                  sVt + buf * 16384 + i * 4096 + w * 1024);
    }
  };

  auto compute = [&](int t, int buf) {
    const int kv0 = t * 64;
    if (kv0 > qw + 31) return;
    const char* kb = sK + buf * 16384;
    const char* vb = sVt + buf * 16384;

    f32x16 sa[2] = {};
    __builtin_amdgcn_s_setprio(1);
#pragma unroll
    for (int ks = 0; ks < 8; ++ks) {
#pragma unroll
      for (int nb = 0; nb < 2; ++nb) {
        const int r = nb * 32 + lo;
        bf16x8 kf = *(const bf16x8*)(kb + (r * 256 + (((ks * 2 + hi) ^ (r & 7)) * 16)));
        sa[nb] = __builtin_amdgcn_mfma_f32_32x32x16_bf16(kf, qf[ks], sa[nb], 0, 0, 0);
      }
    }
    __builtin_amdgcn_s_setprio(0);
    if (kv0 + 63 > qw) {
      const int qg = qw + lo;
#pragma unroll
      for (int nb = 0; nb < 2; ++nb)
#pragma unroll
        for (int r = 0; r < 16; ++r) {
          const int kvg = kv0 + nb * 32 + (r & 3) + 8 * (r >> 2) + 4 * hi;
          if (kvg > qg) sa[nb][r] = -1e30f;
        }
    }
    float pm = -INFINITY;
#pragma unroll
    for (int nb = 0; nb < 2; ++nb)
#pragma unroll
      for (int r = 0; r < 16; ++r) pm = fmaxf(pm, sa[nb][r]);
    pm = fmaxf(pm, __shfl_xor(pm, 32));

    if (__any(pm > mstat + 8.f)) {           // defer-max (T13)
      const float mn = fmaxf(mstat, pm);
      const float rs = __expf(mstat - mn);
      mstat = mn;
      lstat *= rs;
#pragma unroll
      for (int db = 0; db < 4; ++db)
#pragma unroll
        for (int r = 0; r < 16; ++r) ot[db][r] *= rs;
    }

    float ls = 0.f;
    unsigned int pw[2][8];
#pragma unroll
    for (int nb = 0; nb < 2; ++nb)
#pragma unroll
      for (int j = 0; j < 8; ++j) {
        const float e0 = __expf(sa[nb][2 * j]     - mstat);
        const float e1 = __expf(sa[nb][2 * j + 1] - mstat);
        ls += e0 + e1;
        pw[nb][j] = packbf(e0, e1);
      }
    ls += __shfl_xor(ls, 32);
    lstat += ls;

#pragma unroll
    for (int nb = 0; nb < 2; ++nb) {
      unsigned int pj[8];
#pragma unroll
      for (int j = 0; j < 8; ++j) pj[j] = __shfl_xor(pw[nb][j], 32);
      __builtin_amdgcn_s_setprio(1);
#pragma unroll
      for (int half = 0; half < 2; ++half) {
        const int x = half * 4;
        uint32x4 bw;
        bw[0] = hi ? pj[x + 2] : pw[nb][x + 0];
        bw[1] = hi ? pj[x + 3] : pw[nb][x + 1];
        bw[2] = hi ? pw[nb][x + 2] : pj[x + 0];
        bw[3] = hi ? pw[nb][x + 3] : pj[x + 1];
        const bf16x8 pb = __builtin_bit_cast(bf16x8, bw);
        const int ks = nb * 2 + half;
#pragma unroll
        for (int db = 0; db < 4; ++db) {
          const int rv = db * 32 + lo;
          bf16x8 vf = *(const bf16x8*)(vb + (rv * 128 + (((ks * 2 + hi) ^ (rv & 7)) * 16)));
          ot[db] = __builtin_amdgcn_mfma_f32_32x32x16_bf16(vf, pb, ot[db], 0, 0, 0);
        }
      }
      __builtin_amdgcn_s_setprio(0);
    }
  };

  stage(0, 0);
  for (int t = 0; t < nt - 1; ++t) {
    stage(t + 1, (t + 1) & 1);
    asm volatile("s_waitcnt vmcnt(8)" ::: "memory");
    __builtin_amdgcn_s_barrier();
    compute(t, t & 1);
    __builtin_amdgcn_s_barrier();
  }
  asm volatile("s_waitcnt vmcnt(0)" ::: "memory");
  __builtin_amdgcn_s_barrier();
  compute(nt - 1, (nt - 1) & 1);

  __syncthreads();
  char* sO = smem;
  const float inv = 1.f / lstat;
  const int lq = w * 32 + lo;
#pragma unroll
  for (int db = 0; db < 4; ++db) {
#pragma unroll
    for (int j = 0; j < 8; ++j) {
      const int r = 2 * j;
      const int d = db * 32 + (r & 3) + 8 * (r >> 2) + 4 * hi;
      const unsigned int pv = packbf(ot[db][r] * inv, ot[db][r + 1] * inv);
      *(unsigned int*)(sO + (lq * 256 + ((2 * d) ^ (16 * (lq & 7))))) = pv;
    }
  }
  __syncthreads();
  bf16* Og = AO + (size_t)b * T * C + (size_t)h * 128;
#pragma unroll
  for (int i = 0; i < 8; ++i) {
    const int cid = i * 256 + threadIdx.x;
    const int rq = cid >> 4, c = cid & 15;
    bf16x8 vv = *(const bf16x8*)(sO + (rq * 256 + ((c * 16) ^ (16 * (rq & 7)))));
    *(bf16x8*)(Og + (size_t)(q0 + rq) * C + c * 8) = vv;
  }
}

// ---------------------------------------------------------------- launch
extern "C" void kernel_launch(void* const* d_in, const int* in_sizes, int n_in,
                              void* d_out, int out_size, void* d_ws, size_t ws_size,
                              hipStream_t stream) {
  const int B = 2, T = 2048, C = 2048;
  const int M = B * T;  // 4096

  const float* x  = (const float*)d_in[0];
  const float* Wq = (const float*)d_in[1];
  const float* Wk = (const float*)d_in[2];
  const float* Wv = (const float*)d_in[3];
  const float* Wo = (const float*)d_in[4];
  float* out = (float*)d_out;

  char* ws = (char*)d_ws;
  bf16* xb   = (bf16*)(ws);                   // 16,777,216 B
  bf16* wqkv = (bf16*)(ws + 16777216);        // 12,582,912  [3072][2048]
  bf16* wob  = (bf16*)(ws + 29360128);        //  8,388,608
  bf16* Qb   = (bf16*)(ws + 37748736);        // 16,777,216
  bf16* Kb   = (bf16*)(ws + 54525952);        //  4,194,304
  bf16* Vtb  = (bf16*)(ws + 58720256);        //  4,194,304  ([512][4096])
  bf16* AOb  = (bf16*)(ws + 62914560);        // 16,777,216

  const float scale = 0.08838834764831845f;   // 128^-0.5, folded into Wq
  cvt_all<<<2048, 256, 0, stream>>>(x, Wq, Wk, Wv, Wo, xb, wqkv, wob, scale);

  gemm_qkv<<<dim3(24, 32), 256, 0, stream>>>(xb, wqkv, Qb, Kb, Vtb);

  attn_fwd<<<512, 256, 0, stream>>>(Qb, Kb, Vtb, AOb);

  gemm_nt<<<dim3(C / 128, M / 128), 256, 0, stream>>>(AOb, wob, out, M, C, C);
}